// Round 3
// baseline (2667.609 us; speedup 1.0000x reference)
//
#include <hip/hip_runtime.h>
#include <hip/hip_bf16.h>
#include <math.h>

#define HH 512
#define WW 512
#define BC 48
#define IMN (BC * HH * WW)        // 12,582,912
#define GW 544                    // padded width: 16 left + 512 + 16 right
#define GH 545                    // padded height: 16 top + 512 + 17 bottom
#define PST (GH * GW)             // plane stride in elements (296480)

typedef __bf16 v8bf __attribute__((ext_vector_type(8)));
typedef float v16f __attribute__((ext_vector_type(16)));

// ---------------------------------------------------------------------------
// P1: horizontal 32-tap box sum of im -> hs (fp32). One row per block.
// ---------------------------------------------------------------------------
__global__ __launch_bounds__(256) void k_hboxA(const float* __restrict__ src,
                                               float* __restrict__ dst)
{
    __shared__ float s[WW + 32];            // cols -15 .. 528
    const int row = blockIdx.x;             // bc*512 + i
    const long base = (long)row * WW;
    const int tid = threadIdx.x;
    for (int k = tid; k < WW + 32; k += 256) {
        int col = k - 15;
        s[k] = (col >= 0 && col < WW) ? src[base + col] : 0.f;
    }
    __syncthreads();
    for (int j = tid; j < WW; j += 256) {
        float sum = 0.f;
#pragma unroll
        for (int d = 0; d < 32; d++) sum += s[j + d];
        dst[base + j] = sum;
    }
}

// ---------------------------------------------------------------------------
// P3: horizontal 32-tap box sum of squared bf16 im_c (read from padded G0).
// Padding means no bounds checks. Output fp32 H2 -> hs.
// ---------------------------------------------------------------------------
__global__ __launch_bounds__(256) void k_hboxSq(const __hip_bfloat16* __restrict__ G0,
                                                float* __restrict__ dst)
{
    __shared__ float s[GW];
    const int row = blockIdx.x;             // bc*512 + i
    const int plane = row >> 9;
    const int i = row & 511;
    const __hip_bfloat16* rp = G0 + (size_t)plane * PST + (size_t)(16 + i) * GW;
    const int tid = threadIdx.x;
    for (int x = tid; x < GW; x += 256) {
        float v = __bfloat162float(rp[x]);
        s[x] = v * v;
    }
    __syncthreads();
    const long base = (long)row * WW;
    for (int j = tid; j < WW; j += 256) {
        float sum = 0.f;
#pragma unroll
        for (int d = 0; d < 32; d++) sum += s[j + 1 + d];   // idx j+1..j+32 = cols j-15..j+16
        dst[base + j] = sum;
    }
}

// ---------------------------------------------------------------------------
// P2: vertical 32-tap box of hs, center im, write bf16 im_c into padded dual
// copies G0/G1 (G1 shifted left one column). Edge blocks also zero the pads.
// ---------------------------------------------------------------------------
__global__ __launch_bounds__(256) void k_center(const float* __restrict__ hs,
                                                const float* __restrict__ im,
                                                __hip_bfloat16* __restrict__ G0,
                                                __hip_bfloat16* __restrict__ G1)
{
    __shared__ float s[159 * 64];
    const int j0 = blockIdx.x * 64;
    const int i0 = blockIdx.y * 128;
    const int plane = blockIdx.z;
    const int tid = threadIdx.x;
    const size_t iplane = (size_t)plane * HH * WW;
    const size_t gplane = (size_t)plane * PST;
    for (int k = tid; k < 159 * 64; k += 256) {
        int r = k >> 6, c = k & 63;
        int gi = i0 + r - 15;
        s[k] = (gi >= 0 && gi < HH) ? hs[iplane + (size_t)gi * WW + j0 + c] : 0.f;
    }
    __syncthreads();
    const int tc = tid & 63;
    const int lr0 = (tid >> 6) * 32;
    float run = 0.f;
#pragma unroll
    for (int d = 0; d < 32; d++) run += s[(lr0 + d) * 64 + tc];
    for (int rr = 0; rr < 32; rr++) {
        int lr = lr0 + rr;
        int gi = i0 + lr;
        int c = j0 + tc;
        float val = im[iplane + (size_t)gi * WW + c] - run * (1.0f / 1024.0f);
        __hip_bfloat16 w = __float2bfloat16(val);
        size_t pr = gplane + (size_t)(16 + gi) * GW;
        G0[pr + 16 + c] = w;
        G1[pr + 15 + c] = w;
        if (rr < 31) run += s[(lr + 32) * 64 + tc] - s[lr * 64 + tc];
    }
    // ---- pad zeroing (disjoint addresses from all data writes) ----
    if (blockIdx.x == 0) {
        for (int k = tid; k < 128 * 16; k += 256) {
            int rr = k >> 4, x = k & 15;
            size_t pr = gplane + (size_t)(16 + i0 + rr) * GW;
            G0[pr + x] = __float2bfloat16(0.f);
            if (x < 15) G1[pr + x] = __float2bfloat16(0.f);
        }
    }
    if (blockIdx.x == 7) {
        for (int k = tid; k < 128 * 17; k += 256) {
            int rr = k / 17, x = k % 17;
            size_t pr = gplane + (size_t)(16 + i0 + rr) * GW;
            G1[pr + 527 + x] = __float2bfloat16(0.f);
            if (x > 0) G0[pr + 527 + x] = __float2bfloat16(0.f);
        }
    }
    if (blockIdx.x == 0 && blockIdx.y == 0) {
        for (int k = tid; k < 16 * GW; k += 256) {
            G0[gplane + k] = __float2bfloat16(0.f);
            G1[gplane + k] = __float2bfloat16(0.f);
        }
    }
    if (blockIdx.x == 0 && blockIdx.y == 3) {
        size_t b = gplane + (size_t)528 * GW;
        for (int k = tid; k < 17 * GW; k += 256) {
            G0[b + k] = __float2bfloat16(0.f);
            G1[b + k] = __float2bfloat16(0.f);
        }
    }
}

// ---------------------------------------------------------------------------
// P4: vertical 32-tap box of H2 -> energy; normalize G0/G1 in place.
// ---------------------------------------------------------------------------
__global__ __launch_bounds__(256) void k_normalize(const float* __restrict__ hs,
                                                   __hip_bfloat16* __restrict__ G0,
                                                   __hip_bfloat16* __restrict__ G1)
{
    __shared__ float s[159 * 64];
    const int j0 = blockIdx.x * 64;
    const int i0 = blockIdx.y * 128;
    const int plane = blockIdx.z;
    const int tid = threadIdx.x;
    const size_t iplane = (size_t)plane * HH * WW;
    const size_t gplane = (size_t)plane * PST;
    for (int k = tid; k < 159 * 64; k += 256) {
        int r = k >> 6, c = k & 63;
        int gi = i0 + r - 15;
        s[k] = (gi >= 0 && gi < HH) ? hs[iplane + (size_t)gi * WW + j0 + c] : 0.f;
    }
    __syncthreads();
    const int tc = tid & 63;
    const int lr0 = (tid >> 6) * 32;
    float run = 0.f;
#pragma unroll
    for (int d = 0; d < 32; d++) run += s[(lr0 + d) * 64 + tc];
    for (int rr = 0; rr < 32; rr++) {
        int lr = lr0 + rr;
        int gi = i0 + lr;
        int c = j0 + tc;
        float e = sqrtf(fmaxf(run, 0.f));
        size_t pr = gplane + (size_t)(16 + gi) * GW;
        float v = __bfloat162float(G0[pr + 16 + c]) / e;
        __hip_bfloat16 w = __float2bfloat16(v);
        G0[pr + 16 + c] = w;
        G1[pr + 15 + c] = w;
        if (rr < 31) run += s[(lr + 32) * 64 + tc] - s[lr * 64 + tc];
    }
}

// ---------------------------------------------------------------------------
// Template normalization: Tn = (t - mean)/||t - mean|| per (b,c), bf16 out.
// ---------------------------------------------------------------------------
__global__ __launch_bounds__(256) void k_template(const float* __restrict__ t,
                                                  __hip_bfloat16* __restrict__ tn)
{
    __shared__ float red[256];
    const int bc = blockIdx.x, tid = threadIdx.x;
    const float* tp = t + bc * 1024;
    float v0 = tp[tid], v1 = tp[tid + 256], v2 = tp[tid + 512], v3 = tp[tid + 768];
    red[tid] = v0 + v1 + v2 + v3;
    __syncthreads();
    for (int sft = 128; sft > 0; sft >>= 1) {
        if (tid < sft) red[tid] += red[tid + sft];
        __syncthreads();
    }
    float mean = red[0] * (1.0f / 1024.0f);
    __syncthreads();
    float c0 = v0 - mean, c1 = v1 - mean, c2 = v2 - mean, c3 = v3 - mean;
    red[tid] = c0 * c0 + c1 * c1 + c2 * c2 + c3 * c3;
    __syncthreads();
    for (int sft = 128; sft > 0; sft >>= 1) {
        if (tid < sft) red[tid] += red[tid + sft];
        __syncthreads();
    }
    float norm = sqrtf(red[0]);
    __hip_bfloat16* o = tn + bc * 1024;
    o[tid] = __float2bfloat16(c0 / norm);
    o[tid + 256] = __float2bfloat16(c1 / norm);
    o[tid + 512] = __float2bfloat16(c2 / norm);
    o[tid + 768] = __float2bfloat16(c3 / norm);
}

// ---------------------------------------------------------------------------
// Correlation via MFMA scatter scheme, 64 output rows per block (sweep 96),
// 3 waves/SIMD via launch_bounds, explicit 1-deep B-load double buffer.
// Per wave: 32 output cols, 64 output rows.
// P[u][col] = sum_v Tn[u,v] * A[r, col+v-15]; contributes to out[r+15-u][col].
// C/D layout (m74/m101): col=lane&31, row=(reg&3)+8*(reg>>2)+4*(lane>>5).
// ---------------------------------------------------------------------------
__global__ __launch_bounds__(256, 3) void k_corr_mfma(const __hip_bfloat16* __restrict__ G0,
                                                      const __hip_bfloat16* __restrict__ G1,
                                                      const __hip_bfloat16* __restrict__ Tn,
                                                      float* __restrict__ out)
{
    const int tid = threadIdx.x;
    const int wid = tid >> 6;
    const int lane = tid & 63;
    const int n = lane & 31;            // MFMA col (output column within wave tile)
    const int h = lane >> 5;            // lane half
    const int j0w = blockIdx.x * 128 + wid * 32;
    const int i0 = blockIdx.y * 64;     // multiple of 32 (required for static ring idx)
    const int plane = blockIdx.z;

    // A-operand: Tn fragments, loaded once. A[m=u=lane&31][k=v=8h+j (+16)]
    const v8bf* tp = (const v8bf*)(Tn + (size_t)plane * 1024 + n * 32 + 8 * h);
    const v8bf a0 = tp[0];
    const v8bf a1 = tp[2];

    // B pointer: lane's 8 image cols start at c0 = j0w + n - 15 + 8h (+16 for khalf1).
    // Parity-select between G0 and col-shifted G1 so the 16B load is 4B-aligned.
    const int c0 = j0w + n - 15 + 8 * h;
    const int sel = c0 & 1;
    const __hip_bfloat16* gsel = sel ? G1 : G0;
    // phys row for image row r is 16+r; sweep starts at r = i0-15 -> phys i0+1
    const __hip_bfloat16* pb = gsel + (size_t)plane * PST
                             + (size_t)(i0 + 1) * GW + 16 + (c0 - sel);

    float ring[32];
#pragma unroll
    for (int s = 0; s < 32; s++) ring[s] = 0.f;
    const v16f Z = 0.0f;

    // prime the load pipeline (iteration 0)
    v8bf b0 = ((const v8bf*)pb)[0];
    v8bf b1 = ((const v8bf*)pb)[2];

    for (int blk = 0; blk < 3; ++blk) {
#pragma unroll
        for (int t = 0; t < 32; ++t) {
            const int T = 32 * blk + t;
            // prefetch next iteration's B row (row 96 still lands in pad rows)
            const v8bf* rpn = (const v8bf*)(pb + (size_t)(T + 1) * GW);
            v8bf nb0 = rpn[0];
            v8bf nb1 = rpn[2];
            v16f P = __builtin_amdgcn_mfma_f32_32x32x16_bf16(a0, b0, Z, 0, 0, 0);
            P = __builtin_amdgcn_mfma_f32_32x32x16_bf16(a1, b1, P, 0, 0, 0);
            // scatter into rotating ring (phys slot = logical + 4h; add idx static)
#pragma unroll
            for (int q = 0; q < 16; ++q) {
                const int baseq = (q & 3) + 8 * (q >> 2);
                ring[(t - baseq) & 31] += P[q];
            }
            // retire: phys slot (t+1) for h=0, (t+5) for h=1
            float va = ring[(t + 1) & 31];
            float vb = ring[(t + 5) & 31];
            float val = h ? vb : va;
            val += __shfl_xor(val, 32);
            const int ret = i0 - 31 + T;
            if (ret >= i0 && ret < i0 + 64) {
                if (h == 0)
                    out[(size_t)plane * HH * WW + (size_t)ret * WW + j0w + n] = val;
            }
            ring[(t + 1) & 31] = h ? va : 0.f;
            ring[(t + 5) & 31] = h ? 0.f : vb;
            b0 = nb0;
            b1 = nb1;
        }
    }
}

// ---------------------------------------------------------------------------
// Orchestration.
//   d_out : Hsum (P1) -> H2 (P3) -> final output (corr)
//   d_ws  : G0 (bf16 padded), G1 (bf16 padded, col-shifted), Tn (bf16)
// ws needed: 2*48*545*544*2 + 48*1024*2 = 57.0 MB
// ---------------------------------------------------------------------------
extern "C" void kernel_launch(void* const* d_in, const int* in_sizes, int n_in,
                              void* d_out, int out_size, void* d_ws, size_t ws_size,
                              hipStream_t stream)
{
    const float* im = (const float*)d_in[0];
    const float* tmpl = (const float*)d_in[1];
    float* hs = (float*)d_out;
    __hip_bfloat16* G0 = (__hip_bfloat16*)d_ws;
    __hip_bfloat16* G1 = G0 + (size_t)BC * PST;
    __hip_bfloat16* Tn = G1 + (size_t)BC * PST;

    k_template<<<48, 256, 0, stream>>>(tmpl, Tn);
    k_hboxA<<<BC * HH, 256, 0, stream>>>(im, hs);
    k_center<<<dim3(8, 4, BC), 256, 0, stream>>>(hs, im, G0, G1);
    k_hboxSq<<<BC * HH, 256, 0, stream>>>(G0, hs);
    k_normalize<<<dim3(8, 4, BC), 256, 0, stream>>>(hs, G0, G1);
    k_corr_mfma<<<dim3(4, 8, BC), 256, 0, stream>>>(G0, G1, Tn, hs);
}

// Round 4
// 401.038 us; speedup vs baseline: 6.6518x; 6.6518x over previous
//
#include <hip/hip_runtime.h>
#include <hip/hip_bf16.h>
#include <math.h>

#define HH 512
#define WW 512
#define BC 48
#define GW 544                    // padded width: 16 left + 512 + 16 right
#define GH 545                    // padded height: 16 top + 512 + 17 bottom
#define PST (GH * GW)             // plane stride in elements (296480)

// LDS staging geometry for k_corr_mfma
#define ROWB 384                  // staged bytes per row (192 bf16 cols)
#define CHROWS 16                 // rows per chunk
#define COPYSTRIDE 6208           // bytes between parity copies (16B aligned, bank-shifted)
#define BUFSTRIDE (2 * COPYSTRIDE)// bytes per chunk buffer (both copies)
#define LDSBYTES (2 * BUFSTRIDE)  // double buffered = 24832

typedef __bf16 v8bf __attribute__((ext_vector_type(8)));
typedef float v16f __attribute__((ext_vector_type(16)));

// ---------------------------------------------------------------------------
// P1: horizontal 32-tap box sum of im -> hs (fp32). One row per block.
// ---------------------------------------------------------------------------
__global__ __launch_bounds__(256) void k_hboxA(const float* __restrict__ src,
                                               float* __restrict__ dst)
{
    __shared__ float s[WW + 32];            // cols -15 .. 528
    const int row = blockIdx.x;             // bc*512 + i
    const long base = (long)row * WW;
    const int tid = threadIdx.x;
    for (int k = tid; k < WW + 32; k += 256) {
        int col = k - 15;
        s[k] = (col >= 0 && col < WW) ? src[base + col] : 0.f;
    }
    __syncthreads();
    for (int j = tid; j < WW; j += 256) {
        float sum = 0.f;
#pragma unroll
        for (int d = 0; d < 32; d++) sum += s[j + d];
        dst[base + j] = sum;
    }
}

// ---------------------------------------------------------------------------
// P3: horizontal 32-tap box sum of squared bf16 im_c (read from padded G0).
// ---------------------------------------------------------------------------
__global__ __launch_bounds__(256) void k_hboxSq(const __hip_bfloat16* __restrict__ G0,
                                                float* __restrict__ dst)
{
    __shared__ float s[GW];
    const int row = blockIdx.x;             // bc*512 + i
    const int plane = row >> 9;
    const int i = row & 511;
    const __hip_bfloat16* rp = G0 + (size_t)plane * PST + (size_t)(16 + i) * GW;
    const int tid = threadIdx.x;
    for (int x = tid; x < GW; x += 256) {
        float v = __bfloat162float(rp[x]);
        s[x] = v * v;
    }
    __syncthreads();
    const long base = (long)row * WW;
    for (int j = tid; j < WW; j += 256) {
        float sum = 0.f;
#pragma unroll
        for (int d = 0; d < 32; d++) sum += s[j + 1 + d];
        dst[base + j] = sum;
    }
}

// ---------------------------------------------------------------------------
// P2: vertical box + centering -> bf16 dual parity copies G0/G1 (padded).
// ---------------------------------------------------------------------------
__global__ __launch_bounds__(256) void k_center(const float* __restrict__ hs,
                                                const float* __restrict__ im,
                                                __hip_bfloat16* __restrict__ G0,
                                                __hip_bfloat16* __restrict__ G1)
{
    __shared__ float s[159 * 64];
    const int j0 = blockIdx.x * 64;
    const int i0 = blockIdx.y * 128;
    const int plane = blockIdx.z;
    const int tid = threadIdx.x;
    const size_t iplane = (size_t)plane * HH * WW;
    const size_t gplane = (size_t)plane * PST;
    for (int k = tid; k < 159 * 64; k += 256) {
        int r = k >> 6, c = k & 63;
        int gi = i0 + r - 15;
        s[k] = (gi >= 0 && gi < HH) ? hs[iplane + (size_t)gi * WW + j0 + c] : 0.f;
    }
    __syncthreads();
    const int tc = tid & 63;
    const int lr0 = (tid >> 6) * 32;
    float run = 0.f;
#pragma unroll
    for (int d = 0; d < 32; d++) run += s[(lr0 + d) * 64 + tc];
    for (int rr = 0; rr < 32; rr++) {
        int lr = lr0 + rr;
        int gi = i0 + lr;
        int c = j0 + tc;
        float val = im[iplane + (size_t)gi * WW + c] - run * (1.0f / 1024.0f);
        __hip_bfloat16 w = __float2bfloat16(val);
        size_t pr = gplane + (size_t)(16 + gi) * GW;
        G0[pr + 16 + c] = w;
        G1[pr + 15 + c] = w;
        if (rr < 31) run += s[(lr + 32) * 64 + tc] - s[lr * 64 + tc];
    }
    if (blockIdx.x == 0) {
        for (int k = tid; k < 128 * 16; k += 256) {
            int rr = k >> 4, x = k & 15;
            size_t pr = gplane + (size_t)(16 + i0 + rr) * GW;
            G0[pr + x] = __float2bfloat16(0.f);
            if (x < 15) G1[pr + x] = __float2bfloat16(0.f);
        }
    }
    if (blockIdx.x == 7) {
        for (int k = tid; k < 128 * 17; k += 256) {
            int rr = k / 17, x = k % 17;
            size_t pr = gplane + (size_t)(16 + i0 + rr) * GW;
            G1[pr + 527 + x] = __float2bfloat16(0.f);
            if (x > 0) G0[pr + 527 + x] = __float2bfloat16(0.f);
        }
    }
    if (blockIdx.x == 0 && blockIdx.y == 0) {
        for (int k = tid; k < 16 * GW; k += 256) {
            G0[gplane + k] = __float2bfloat16(0.f);
            G1[gplane + k] = __float2bfloat16(0.f);
        }
    }
    if (blockIdx.x == 0 && blockIdx.y == 3) {
        size_t b = gplane + (size_t)528 * GW;
        for (int k = tid; k < 17 * GW; k += 256) {
            G0[b + k] = __float2bfloat16(0.f);
            G1[b + k] = __float2bfloat16(0.f);
        }
    }
}

// ---------------------------------------------------------------------------
// P4: vertical box of H2 -> energy; normalize G0/G1 in place.
// ---------------------------------------------------------------------------
__global__ __launch_bounds__(256) void k_normalize(const float* __restrict__ hs,
                                                   __hip_bfloat16* __restrict__ G0,
                                                   __hip_bfloat16* __restrict__ G1)
{
    __shared__ float s[159 * 64];
    const int j0 = blockIdx.x * 64;
    const int i0 = blockIdx.y * 128;
    const int plane = blockIdx.z;
    const int tid = threadIdx.x;
    const size_t iplane = (size_t)plane * HH * WW;
    const size_t gplane = (size_t)plane * PST;
    for (int k = tid; k < 159 * 64; k += 256) {
        int r = k >> 6, c = k & 63;
        int gi = i0 + r - 15;
        s[k] = (gi >= 0 && gi < HH) ? hs[iplane + (size_t)gi * WW + j0 + c] : 0.f;
    }
    __syncthreads();
    const int tc = tid & 63;
    const int lr0 = (tid >> 6) * 32;
    float run = 0.f;
#pragma unroll
    for (int d = 0; d < 32; d++) run += s[(lr0 + d) * 64 + tc];
    for (int rr = 0; rr < 32; rr++) {
        int lr = lr0 + rr;
        int gi = i0 + lr;
        int c = j0 + tc;
        float e = sqrtf(fmaxf(run, 0.f));
        size_t pr = gplane + (size_t)(16 + gi) * GW;
        float v = __bfloat162float(G0[pr + 16 + c]) / e;
        __hip_bfloat16 w = __float2bfloat16(v);
        G0[pr + 16 + c] = w;
        G1[pr + 15 + c] = w;
        if (rr < 31) run += s[(lr + 32) * 64 + tc] - s[lr * 64 + tc];
    }
}

// ---------------------------------------------------------------------------
// Template normalization: Tn = (t - mean)/||t - mean|| per (b,c), bf16 out.
// ---------------------------------------------------------------------------
__global__ __launch_bounds__(256) void k_template(const float* __restrict__ t,
                                                  __hip_bfloat16* __restrict__ tn)
{
    __shared__ float red[256];
    const int bc = blockIdx.x, tid = threadIdx.x;
    const float* tp = t + bc * 1024;
    float v0 = tp[tid], v1 = tp[tid + 256], v2 = tp[tid + 512], v3 = tp[tid + 768];
    red[tid] = v0 + v1 + v2 + v3;
    __syncthreads();
    for (int sft = 128; sft > 0; sft >>= 1) {
        if (tid < sft) red[tid] += red[tid + sft];
        __syncthreads();
    }
    float mean = red[0] * (1.0f / 1024.0f);
    __syncthreads();
    float c0 = v0 - mean, c1 = v1 - mean, c2 = v2 - mean, c3 = v3 - mean;
    red[tid] = c0 * c0 + c1 * c1 + c2 * c2 + c3 * c3;
    __syncthreads();
    for (int sft = 128; sft > 0; sft >>= 1) {
        if (tid < sft) red[tid] += red[tid + sft];
        __syncthreads();
    }
    float norm = sqrtf(red[0]);
    __hip_bfloat16* o = tn + bc * 1024;
    o[tid] = __float2bfloat16(c0 / norm);
    o[tid + 256] = __float2bfloat16(c1 / norm);
    o[tid + 512] = __float2bfloat16(c2 / norm);
    o[tid + 768] = __float2bfloat16(c3 / norm);
}

// ---------------------------------------------------------------------------
// Async stage of one 16-row chunk (both parity copies) into LDS buffer b.
// 6 calls x 1024B per copy: lane's bytes q = c2*1024 + lane*16 map to
// row q/384, in-row byte q%384. laneoffs precomputed in elements.
// ---------------------------------------------------------------------------
__device__ __forceinline__ void stage_chunk(const __hip_bfloat16* g0,
                                            const __hip_bfloat16* g1,
                                            const int* laneoffs,
                                            char* ldsbase, int whichbuf)
{
    char* d = ldsbase + whichbuf * BUFSTRIDE;
#pragma unroll
    for (int c2 = 0; c2 < 6; ++c2) {
        __builtin_amdgcn_global_load_lds(
            (const __attribute__((address_space(1))) void*)(g0 + laneoffs[c2]),
            (__attribute__((address_space(3))) void*)(d + c2 * 1024),
            16, 0, 0);
        __builtin_amdgcn_global_load_lds(
            (const __attribute__((address_space(1))) void*)(g1 + laneoffs[c2]),
            (__attribute__((address_space(3))) void*)(d + COPYSTRIDE + c2 * 1024),
            16, 0, 0);
    }
}

// ---------------------------------------------------------------------------
// Compute 16 sweep iterations from LDS buffer PHASE (chunk parity == PHASE).
// Ring slot arithmetic identical to the validated version with t -> 16*PHASE+t.
// ---------------------------------------------------------------------------
template <int PHASE>
__device__ __forceinline__ void compute_chunk(const unsigned int* __restrict__ Lr,
                                              v8bf a0, v8bf a1,
                                              float (&ring)[32],
                                              int h, int Tbase, int i0,
                                              float* outp)
{
    const v16f Z = 0.0f;
#pragma unroll
    for (int t = 0; t < 16; ++t) {
        const int tt = PHASE * 16 + t;
        const unsigned int* p = Lr + PHASE * (BUFSTRIDE / 4) + t * (ROWB / 4);
        union { unsigned int u[4]; v8bf v; } B0, B1;
        B0.u[0] = p[0];  B0.u[1] = p[1];  B0.u[2] = p[2];  B0.u[3] = p[3];
        B1.u[0] = p[8];  B1.u[1] = p[9];  B1.u[2] = p[10]; B1.u[3] = p[11];
        v16f P = __builtin_amdgcn_mfma_f32_32x32x16_bf16(a0, B0.v, Z, 0, 0, 0);
        P = __builtin_amdgcn_mfma_f32_32x32x16_bf16(a1, B1.v, P, 0, 0, 0);
#pragma unroll
        for (int q = 0; q < 16; ++q) {
            const int baseq = (q & 3) + 8 * (q >> 2);
            ring[(tt - baseq) & 31] += P[q];
        }
        float va = ring[(tt + 1) & 31];
        float vb = ring[(tt + 5) & 31];
        float val = h ? vb : va;
        val += __shfl_xor(val, 32);
        const int ret = i0 - 31 + Tbase + t;
        if (ret >= i0 && ret < i0 + 64) {
            if (h == 0) outp[(size_t)ret * WW] = val;
        }
        ring[(tt + 1) & 31] = h ? va : 0.f;
        ring[(tt + 5) & 31] = h ? 0.f : vb;
    }
}

// ---------------------------------------------------------------------------
// Correlation: MFMA scatter scheme + async LDS double-buffer staging.
// Block: 4 waves, 128 output cols x 64 output rows, sweep 96 image rows
// in 6 chunks of 16. Each staged row holds cols j0-16 .. j0+175 in two
// parity copies so every lane's fragment read is 4B-aligned dwords.
// ---------------------------------------------------------------------------
__global__ __launch_bounds__(256) void k_corr_mfma(const __hip_bfloat16* __restrict__ G0,
                                                   const __hip_bfloat16* __restrict__ G1,
                                                   const __hip_bfloat16* __restrict__ Tn,
                                                   float* __restrict__ out)
{
    __shared__ __align__(16) char lds[LDSBYTES];
    const int tid = threadIdx.x;
    const int wid = tid >> 6;
    const int lane = tid & 63;
    const int n = lane & 31;
    const int h = lane >> 5;
    const int j0 = blockIdx.x * 128;
    const int j0w = j0 + wid * 32;
    const int i0 = blockIdx.y * 64;
    const int plane = blockIdx.z;

    // A-operand: Tn fragments (whole template in registers)
    const v8bf* tp = (const v8bf*)(Tn + (size_t)plane * 1024 + n * 32 + 8 * h);
    const v8bf a0 = tp[0];
    const v8bf a1 = tp[2];

    // Reader setup: parity copy + dword base within a staged row
    const int c0 = j0w + n - 15 + 8 * h;
    const int sel = c0 & 1;
    const int dbase = (32 * wid + n + 1 + 8 * h - sel) >> 1;
    const unsigned int* Lr = (const unsigned int*)(lds + sel * COPYSTRIDE) + dbase;

    // Stager setup: per-lane element offsets for the 6 calls per copy
    int laneoffs[6];
#pragma unroll
    for (int c2 = 0; c2 < 6; ++c2) {
        int q = c2 * 1024 + lane * 16;
        int rl = q / ROWB;
        int cb = q - rl * ROWB;
        laneoffs[c2] = rl * GW + (cb >> 1);
    }
    // chunk 0 source: phys row i0+1, element col base j0 (= image col j0-16)
    const __hip_bfloat16* g0p = G0 + (size_t)plane * PST + (size_t)(i0 + 1) * GW + j0;
    const __hip_bfloat16* g1p = G1 + (size_t)plane * PST + (size_t)(i0 + 1) * GW + j0;

    float ring[32];
#pragma unroll
    for (int s = 0; s < 32; s++) ring[s] = 0.f;

    float* outp = out + (size_t)plane * HH * WW + j0w + n;

    stage_chunk(g0p, g1p, laneoffs, lds, 0);
    stage_chunk(g0p + 16 * GW, g1p + 16 * GW, laneoffs, lds, 1);
    __syncthreads();

    for (int k2 = 0; k2 < 3; ++k2) {
        compute_chunk<0>(Lr, a0, a1, ring, h, 32 * k2, i0, outp);
        __syncthreads();
        if (k2 < 2)
            stage_chunk(g0p + (size_t)(32 * k2 + 32) * GW,
                        g1p + (size_t)(32 * k2 + 32) * GW, laneoffs, lds, 0);
        compute_chunk<1>(Lr, a0, a1, ring, h, 32 * k2 + 16, i0, outp);
        __syncthreads();
        if (k2 < 2)
            stage_chunk(g0p + (size_t)(32 * k2 + 48) * GW,
                        g1p + (size_t)(32 * k2 + 48) * GW, laneoffs, lds, 1);
    }
}

// ---------------------------------------------------------------------------
// Orchestration.
//   d_out : Hsum (P1) -> H2 (P3) -> final output (corr)
//   d_ws  : G0, G1 (bf16 padded dual copies), Tn (bf16)  — ~57 MB
// ---------------------------------------------------------------------------
extern "C" void kernel_launch(void* const* d_in, const int* in_sizes, int n_in,
                              void* d_out, int out_size, void* d_ws, size_t ws_size,
                              hipStream_t stream)
{
    const float* im = (const float*)d_in[0];
    const float* tmpl = (const float*)d_in[1];
    float* hs = (float*)d_out;
    __hip_bfloat16* G0 = (__hip_bfloat16*)d_ws;
    __hip_bfloat16* G1 = G0 + (size_t)BC * PST;
    __hip_bfloat16* Tn = G1 + (size_t)BC * PST;

    k_template<<<48, 256, 0, stream>>>(tmpl, Tn);
    k_hboxA<<<BC * HH, 256, 0, stream>>>(im, hs);
    k_center<<<dim3(8, 4, BC), 256, 0, stream>>>(hs, im, G0, G1);
    k_hboxSq<<<BC * HH, 256, 0, stream>>>(G0, hs);
    k_normalize<<<dim3(8, 4, BC), 256, 0, stream>>>(hs, G0, G1);
    k_corr_mfma<<<dim3(4, 8, BC), 256, 0, stream>>>(G0, G1, Tn, hs);
}

// Round 5
// 354.744 us; speedup vs baseline: 7.5198x; 1.1305x over previous
//
#include <hip/hip_runtime.h>
#include <hip/hip_bf16.h>
#include <math.h>

#define HH 512
#define WW 512
#define BC 48
#define GW 544                    // padded width: 16 left + 512 + 16 right
#define GH 545                    // padded height: 16 top + 512 + 17 bottom
#define PST (GH * GW)             // plane stride in elements (296480)

// LDS staging geometry for k_corr_mfma
#define ROWB 384                  // staged bytes per row (192 bf16 cols)
#define COPYSTRIDE 6208           // bytes between parity copies (16B aligned, bank-shifted)
#define BUFSTRIDE (2 * COPYSTRIDE)// bytes per chunk buffer (both copies)
#define LDSBYTES (2 * BUFSTRIDE)  // double buffered = 24832

typedef __bf16 v8bf __attribute__((ext_vector_type(8)));
typedef float v16f __attribute__((ext_vector_type(16)));

// ---------------------------------------------------------------------------
// P1: horizontal 32-tap box sum of im -> hs (fp32). One row per block.
// ---------------------------------------------------------------------------
__global__ __launch_bounds__(256) void k_hboxA(const float* __restrict__ src,
                                               float* __restrict__ dst)
{
    __shared__ float s[WW + 32];            // cols -15 .. 528
    const int row = blockIdx.x;             // bc*512 + i
    const long base = (long)row * WW;
    const int tid = threadIdx.x;
    for (int k = tid; k < WW + 32; k += 256) {
        int col = k - 15;
        s[k] = (col >= 0 && col < WW) ? src[base + col] : 0.f;
    }
    __syncthreads();
    for (int j = tid; j < WW; j += 256) {
        float sum = 0.f;
#pragma unroll
        for (int d = 0; d < 32; d++) sum += s[j + d];
        dst[base + j] = sum;
    }
}

// ---------------------------------------------------------------------------
// P3: horizontal 32-tap box sum of squared bf16 im_c (read from padded G0).
// ---------------------------------------------------------------------------
__global__ __launch_bounds__(256) void k_hboxSq(const __hip_bfloat16* __restrict__ G0,
                                                float* __restrict__ dst)
{
    __shared__ float s[GW];
    const int row = blockIdx.x;             // bc*512 + i
    const int plane = row >> 9;
    const int i = row & 511;
    const __hip_bfloat16* rp = G0 + (size_t)plane * PST + (size_t)(16 + i) * GW;
    const int tid = threadIdx.x;
    for (int x = tid; x < GW; x += 256) {
        float v = __bfloat162float(rp[x]);
        s[x] = v * v;
    }
    __syncthreads();
    const long base = (long)row * WW;
    for (int j = tid; j < WW; j += 256) {
        float sum = 0.f;
#pragma unroll
        for (int d = 0; d < 32; d++) sum += s[j + 1 + d];
        dst[base + j] = sum;
    }
}

// ---------------------------------------------------------------------------
// P2: vertical box + centering -> bf16 dual parity copies G0/G1 (padded).
// ---------------------------------------------------------------------------
__global__ __launch_bounds__(256) void k_center(const float* __restrict__ hs,
                                                const float* __restrict__ im,
                                                __hip_bfloat16* __restrict__ G0,
                                                __hip_bfloat16* __restrict__ G1)
{
    __shared__ float s[159 * 64];
    const int j0 = blockIdx.x * 64;
    const int i0 = blockIdx.y * 128;
    const int plane = blockIdx.z;
    const int tid = threadIdx.x;
    const size_t iplane = (size_t)plane * HH * WW;
    const size_t gplane = (size_t)plane * PST;
    for (int k = tid; k < 159 * 64; k += 256) {
        int r = k >> 6, c = k & 63;
        int gi = i0 + r - 15;
        s[k] = (gi >= 0 && gi < HH) ? hs[iplane + (size_t)gi * WW + j0 + c] : 0.f;
    }
    __syncthreads();
    const int tc = tid & 63;
    const int lr0 = (tid >> 6) * 32;
    float run = 0.f;
#pragma unroll
    for (int d = 0; d < 32; d++) run += s[(lr0 + d) * 64 + tc];
    for (int rr = 0; rr < 32; rr++) {
        int lr = lr0 + rr;
        int gi = i0 + lr;
        int c = j0 + tc;
        float val = im[iplane + (size_t)gi * WW + c] - run * (1.0f / 1024.0f);
        __hip_bfloat16 w = __float2bfloat16(val);
        size_t pr = gplane + (size_t)(16 + gi) * GW;
        G0[pr + 16 + c] = w;
        G1[pr + 15 + c] = w;
        if (rr < 31) run += s[(lr + 32) * 64 + tc] - s[lr * 64 + tc];
    }
    if (blockIdx.x == 0) {
        for (int k = tid; k < 128 * 16; k += 256) {
            int rr = k >> 4, x = k & 15;
            size_t pr = gplane + (size_t)(16 + i0 + rr) * GW;
            G0[pr + x] = __float2bfloat16(0.f);
            if (x < 15) G1[pr + x] = __float2bfloat16(0.f);
        }
    }
    if (blockIdx.x == 7) {
        for (int k = tid; k < 128 * 17; k += 256) {
            int rr = k / 17, x = k % 17;
            size_t pr = gplane + (size_t)(16 + i0 + rr) * GW;
            G1[pr + 527 + x] = __float2bfloat16(0.f);
            if (x > 0) G0[pr + 527 + x] = __float2bfloat16(0.f);
        }
    }
    if (blockIdx.x == 0 && blockIdx.y == 0) {
        for (int k = tid; k < 16 * GW; k += 256) {
            G0[gplane + k] = __float2bfloat16(0.f);
            G1[gplane + k] = __float2bfloat16(0.f);
        }
    }
    if (blockIdx.x == 0 && blockIdx.y == 3) {
        size_t b = gplane + (size_t)528 * GW;
        for (int k = tid; k < 17 * GW; k += 256) {
            G0[b + k] = __float2bfloat16(0.f);
            G1[b + k] = __float2bfloat16(0.f);
        }
    }
}

// ---------------------------------------------------------------------------
// P4: vertical box of H2 -> energy; normalize G0/G1 in place.
// ---------------------------------------------------------------------------
__global__ __launch_bounds__(256) void k_normalize(const float* __restrict__ hs,
                                                   __hip_bfloat16* __restrict__ G0,
                                                   __hip_bfloat16* __restrict__ G1)
{
    __shared__ float s[159 * 64];
    const int j0 = blockIdx.x * 64;
    const int i0 = blockIdx.y * 128;
    const int plane = blockIdx.z;
    const int tid = threadIdx.x;
    const size_t iplane = (size_t)plane * HH * WW;
    const size_t gplane = (size_t)plane * PST;
    for (int k = tid; k < 159 * 64; k += 256) {
        int r = k >> 6, c = k & 63;
        int gi = i0 + r - 15;
        s[k] = (gi >= 0 && gi < HH) ? hs[iplane + (size_t)gi * WW + j0 + c] : 0.f;
    }
    __syncthreads();
    const int tc = tid & 63;
    const int lr0 = (tid >> 6) * 32;
    float run = 0.f;
#pragma unroll
    for (int d = 0; d < 32; d++) run += s[(lr0 + d) * 64 + tc];
    for (int rr = 0; rr < 32; rr++) {
        int lr = lr0 + rr;
        int gi = i0 + lr;
        int c = j0 + tc;
        float e = sqrtf(fmaxf(run, 0.f));
        size_t pr = gplane + (size_t)(16 + gi) * GW;
        float v = __bfloat162float(G0[pr + 16 + c]) / e;
        __hip_bfloat16 w = __float2bfloat16(v);
        G0[pr + 16 + c] = w;
        G1[pr + 15 + c] = w;
        if (rr < 31) run += s[(lr + 32) * 64 + tc] - s[lr * 64 + tc];
    }
}

// ---------------------------------------------------------------------------
// Template normalization: Tn = (t - mean)/||t - mean|| per (b,c), bf16 out.
// ---------------------------------------------------------------------------
__global__ __launch_bounds__(256) void k_template(const float* __restrict__ t,
                                                  __hip_bfloat16* __restrict__ tn)
{
    __shared__ float red[256];
    const int bc = blockIdx.x, tid = threadIdx.x;
    const float* tp = t + bc * 1024;
    float v0 = tp[tid], v1 = tp[tid + 256], v2 = tp[tid + 512], v3 = tp[tid + 768];
    red[tid] = v0 + v1 + v2 + v3;
    __syncthreads();
    for (int sft = 128; sft > 0; sft >>= 1) {
        if (tid < sft) red[tid] += red[tid + sft];
        __syncthreads();
    }
    float mean = red[0] * (1.0f / 1024.0f);
    __syncthreads();
    float c0 = v0 - mean, c1 = v1 - mean, c2 = v2 - mean, c3 = v3 - mean;
    red[tid] = c0 * c0 + c1 * c1 + c2 * c2 + c3 * c3;
    __syncthreads();
    for (int sft = 128; sft > 0; sft >>= 1) {
        if (tid < sft) red[tid] += red[tid + sft];
        __syncthreads();
    }
    float norm = sqrtf(red[0]);
    __hip_bfloat16* o = tn + bc * 1024;
    o[tid] = __float2bfloat16(c0 / norm);
    o[tid + 256] = __float2bfloat16(c1 / norm);
    o[tid + 512] = __float2bfloat16(c2 / norm);
    o[tid + 768] = __float2bfloat16(c3 / norm);
}

// ---------------------------------------------------------------------------
// Compute 16 sweep iterations from LDS buffer PHASE. Ring slot arithmetic
// identical to the validated version (t -> 16*PHASE + t). Retire work only
// inside the wave-uniform live range T in [31,94]; slot zeroing unconditional.
// ---------------------------------------------------------------------------
template <int PHASE>
__device__ __forceinline__ void compute_chunk(const unsigned int* __restrict__ Lr,
                                              v8bf a0, v8bf a1,
                                              float (&ring)[32],
                                              int h, int Tbase, int i0,
                                              float* outp)
{
    const v16f Z = 0.0f;
#pragma unroll
    for (int t = 0; t < 16; ++t) {
        const int tt = PHASE * 16 + t;
        const unsigned int* p = Lr + PHASE * (BUFSTRIDE / 4) + t * (ROWB / 4);
        union { unsigned int u[4]; v8bf v; } B0, B1;
        B0.u[0] = p[0];  B0.u[1] = p[1];  B0.u[2] = p[2];  B0.u[3] = p[3];
        B1.u[0] = p[8];  B1.u[1] = p[9];  B1.u[2] = p[10]; B1.u[3] = p[11];
        v16f P = __builtin_amdgcn_mfma_f32_32x32x16_bf16(a0, B0.v, Z, 0, 0, 0);
        P = __builtin_amdgcn_mfma_f32_32x32x16_bf16(a1, B1.v, P, 0, 0, 0);
#pragma unroll
        for (int q = 0; q < 16; ++q) {
            const int baseq = (q & 3) + 8 * (q >> 2);
            ring[(tt - baseq) & 31] += P[q];
        }
        const int T = Tbase + t;                 // wave-uniform
        float va = ring[(tt + 1) & 31];
        float vb = ring[(tt + 5) & 31];
        if (T >= 31 && T <= 94) {                // uniform branch: skip dead retires
            float val = h ? vb : va;
            val += __shfl_xor(val, 32);
            const int ret = i0 - 31 + T;
            if (h == 0) outp[(size_t)ret * WW] = val;
        }
        ring[(tt + 1) & 31] = h ? va : 0.f;      // zeroing must stay unconditional
        ring[(tt + 5) & 31] = h ? 0.f : vb;
    }
}

// ---------------------------------------------------------------------------
// Correlation: MFMA scatter scheme + async LDS double-buffer staging.
// Block: 4 waves, 128 output cols x 64 output rows, sweep 96 image rows in
// 6 chunks of 16. Staging of the 12 x 1KB segments per chunk is SPLIT across
// the 4 waves (3 segments each); barrier semantics guarantee completeness.
// ---------------------------------------------------------------------------
__global__ __launch_bounds__(256) void k_corr_mfma(const __hip_bfloat16* __restrict__ G0,
                                                   const __hip_bfloat16* __restrict__ G1,
                                                   const __hip_bfloat16* __restrict__ Tn,
                                                   float* __restrict__ out)
{
    __shared__ __align__(16) char lds[LDSBYTES];
    const int tid = threadIdx.x;
    const int wid = tid >> 6;
    const int lane = tid & 63;
    const int n = lane & 31;
    const int h = lane >> 5;
    const int j0 = blockIdx.x * 128;
    const int j0w = j0 + wid * 32;
    const int i0 = blockIdx.y * 64;
    const int plane = blockIdx.z;

    // A-operand: Tn fragments (whole template in registers)
    const v8bf* tp = (const v8bf*)(Tn + (size_t)plane * 1024 + n * 32 + 8 * h);
    const v8bf a0 = tp[0];
    const v8bf a1 = tp[2];

    // Reader setup: parity copy + dword base within a staged row
    const int c0 = j0w + n - 15 + 8 * h;
    const int sel = c0 & 1;
    const int dbase = (32 * wid + n + 1 + 8 * h - sel) >> 1;
    const unsigned int* Lr = (const unsigned int*)(lds + sel * COPYSTRIDE) + dbase;

    // chunk 0 source: phys row i0+1, element col base j0 (= image col j0-16)
    const __hip_bfloat16* g0p = G0 + (size_t)plane * PST + (size_t)(i0 + 1) * GW + j0;
    const __hip_bfloat16* g1p = G1 + (size_t)plane * PST + (size_t)(i0 + 1) * GW + j0;

    // Stager setup: this wave's 3 of the 12 segments (s = wid, wid+4, wid+8)
    const __hip_bfloat16* srcp[3];
    int ldso[3];
#pragma unroll
    for (int k = 0; k < 3; ++k) {
        int s = wid + 4 * k;
        int cp = (s >= 6) ? 1 : 0;
        int c2 = cp ? (s - 6) : s;
        int q = c2 * 1024 + lane * 16;
        int rl = q / ROWB;
        int cb = q - rl * ROWB;
        srcp[k] = (cp ? g1p : g0p) + rl * GW + (cb >> 1);
        ldso[k] = cp * COPYSTRIDE + c2 * 1024;
    }

    float ring[32];
#pragma unroll
    for (int s = 0; s < 32; s++) ring[s] = 0.f;

    float* outp = out + (size_t)plane * HH * WW + j0w + n;

    // stage chunk R (rows [R,R+16)) into buffer b — this wave's 3 segments only
    auto stage = [&](int R, int b) {
#pragma unroll
        for (int k = 0; k < 3; ++k) {
            __builtin_amdgcn_global_load_lds(
                (const __attribute__((address_space(1))) void*)(srcp[k] + (size_t)R * GW),
                (__attribute__((address_space(3))) void*)(lds + b * BUFSTRIDE + ldso[k]),
                16, 0, 0);
        }
    };

    stage(0, 0);
    stage(16, 1);
    __syncthreads();

    for (int k2 = 0; k2 < 3; ++k2) {
        compute_chunk<0>(Lr, a0, a1, ring, h, 32 * k2, i0, outp);
        __syncthreads();
        if (k2 < 2) stage(32 * k2 + 32, 0);
        compute_chunk<1>(Lr, a0, a1, ring, h, 32 * k2 + 16, i0, outp);
        __syncthreads();
        if (k2 < 2) stage(32 * k2 + 48, 1);
    }
}

// ---------------------------------------------------------------------------
// Orchestration.
//   d_out : Hsum (P1) -> H2 (P3) -> final output (corr)
//   d_ws  : G0, G1 (bf16 padded dual copies), Tn (bf16)  — ~57 MB
// ---------------------------------------------------------------------------
extern "C" void kernel_launch(void* const* d_in, const int* in_sizes, int n_in,
                              void* d_out, int out_size, void* d_ws, size_t ws_size,
                              hipStream_t stream)
{
    const float* im = (const float*)d_in[0];
    const float* tmpl = (const float*)d_in[1];
    float* hs = (float*)d_out;
    __hip_bfloat16* G0 = (__hip_bfloat16*)d_ws;
    __hip_bfloat16* G1 = G0 + (size_t)BC * PST;
    __hip_bfloat16* Tn = G1 + (size_t)BC * PST;

    k_template<<<48, 256, 0, stream>>>(tmpl, Tn);
    k_hboxA<<<BC * HH, 256, 0, stream>>>(im, hs);
    k_center<<<dim3(8, 4, BC), 256, 0, stream>>>(hs, im, G0, G1);
    k_hboxSq<<<BC * HH, 256, 0, stream>>>(G0, hs);
    k_normalize<<<dim3(8, 4, BC), 256, 0, stream>>>(hs, G0, G1);
    k_corr_mfma<<<dim3(4, 8, BC), 256, 0, stream>>>(G0, G1, Tn, hs);
}